// Round 1
// baseline (54.714 us; speedup 1.0000x reference)
//
#include <hip/hip_runtime.h>

// BasisVQ: quantized[b,k,:] = basis[argmax_c latent[b,k,c], :]
//          indices[b,k]     = argmax_c latent[b,k,c]
// B=16, K=2048, C=1024, D=900. Output = [quantized (B*K*D f32), indices (B*K as f32)].

#define C_DIM 1024
#define D_DIM 900

__global__ __launch_bounds__(256) void basisvq_kernel(
    const float* __restrict__ latent,   // [ROWS, 1024]
    const float* __restrict__ basis,    // [1024, 900]
    float* __restrict__ out_q,          // [ROWS, 900]
    float* __restrict__ out_idx)        // [ROWS]
{
    const int row = blockIdx.x;
    const int tid = threadIdx.x;

    // ---- per-thread argmax over its 4 contiguous elements (float4 load) ----
    const float4* lrow = reinterpret_cast<const float4*>(latent + (size_t)row * C_DIM);
    float4 v = lrow[tid];
    float m = v.x;
    int mi  = tid * 4;
    if (v.y > m) { m = v.y; mi = tid * 4 + 1; }
    if (v.z > m) { m = v.z; mi = tid * 4 + 2; }
    if (v.w > m) { m = v.w; mi = tid * 4 + 3; }

    // ---- wave(64)-level argmax reduce, first-index-wins on ties ----
    #pragma unroll
    for (int off = 32; off > 0; off >>= 1) {
        float om = __shfl_down(m, off, 64);
        int   oi = __shfl_down(mi, off, 64);
        if (om > m || (om == m && oi < mi)) { m = om; mi = oi; }
    }

    // ---- cross-wave reduce via LDS (4 waves / block) ----
    __shared__ float sm[4];
    __shared__ int   si[4];
    __shared__ int   bidx;
    const int lane = tid & 63;
    const int wid  = tid >> 6;
    if (lane == 0) { sm[wid] = m; si[wid] = mi; }
    __syncthreads();
    if (tid == 0) {
        float bm = sm[0]; int bi = si[0];
        #pragma unroll
        for (int w = 1; w < 4; ++w) {
            if (sm[w] > bm || (sm[w] == bm && si[w] < bi)) { bm = sm[w]; bi = si[w]; }
        }
        bidx = bi;
        out_idx[row] = (float)bi;
    }
    __syncthreads();
    const int idx = bidx;

    // ---- gather: copy basis[idx, 0:900] -> out_q[row, 0:900] as float4 ----
    // 900 floats = 225 float4; row base byte offset row*3600 is 16B-aligned.
    const float4* b4 = reinterpret_cast<const float4*>(basis + (size_t)idx * D_DIM);
    float4*       o4 = reinterpret_cast<float4*>(out_q + (size_t)row * D_DIM);
    if (tid < 225) o4[tid] = b4[tid];
}

extern "C" void kernel_launch(void* const* d_in, const int* in_sizes, int n_in,
                              void* d_out, int out_size, void* d_ws, size_t ws_size,
                              hipStream_t stream) {
    const float* latent = (const float*)d_in[0];   // 16*2048*1024
    const float* basis  = (const float*)d_in[1];   // 1024*900
    (void)n_in; (void)d_ws; (void)ws_size;

    const int rows = in_sizes[0] / C_DIM;          // 32768
    float* out_q   = (float*)d_out;                // rows*900
    float* out_idx = (float*)d_out + (size_t)rows * D_DIM;
    (void)out_size;

    basisvq_kernel<<<rows, 256, 0, stream>>>(latent, basis, out_q, out_idx);
}

// Round 2
// 50.511 us; speedup vs baseline: 1.0832x; 1.0832x over previous
//
#include <hip/hip_runtime.h>

// BasisVQ: quantized[b,k,:] = basis[argmax_c latent[b,k,c], :]
//          indices[b,k]     = argmax_c latent[b,k,c]
// B=16, K=2048, C=1024, D=900. Output = [quantized (B*K*D f32), indices (B*K as f32)].
//
// R2: one WAVE per row (no LDS, no barriers), shfl_xor butterfly argmax,
//     nontemporal loads/stores for the streaming tensors so the 3.6 MB basis
//     table stays resident in each XCD's 4 MB L2.

#define C_DIM 1024
#define D_DIM 900

typedef float vfloat4 __attribute__((ext_vector_type(4)));

__global__ __launch_bounds__(256) void basisvq_kernel(
    const float* __restrict__ latent,   // [ROWS, 1024]
    const float* __restrict__ basis,    // [1024, 900]
    float* __restrict__ out_q,          // [ROWS, 900]
    float* __restrict__ out_idx,        // [ROWS]
    int rows)
{
    const int lane = threadIdx.x & 63;
    const int wid  = threadIdx.x >> 6;
    const int row  = blockIdx.x * 4 + wid;
    if (row >= rows) return;

    // ---- load 16 latent floats/lane as 4 independent nontemporal float4 ----
    const vfloat4* lrow = reinterpret_cast<const vfloat4*>(latent + (size_t)row * C_DIM);
    vfloat4 v0 = __builtin_nontemporal_load(&lrow[lane]);
    vfloat4 v1 = __builtin_nontemporal_load(&lrow[lane + 64]);
    vfloat4 v2 = __builtin_nontemporal_load(&lrow[lane + 128]);
    vfloat4 v3 = __builtin_nontemporal_load(&lrow[lane + 192]);

    // ---- per-lane argmax, first-index-wins (scan in increasing c, strict >) ----
    float m = v0[0];
    int   mi = lane * 4;
    #pragma unroll
    for (int e = 1; e < 4; ++e)
        if (v0[e] > m) { m = v0[e]; mi = lane * 4 + e; }
    #pragma unroll
    for (int e = 0; e < 4; ++e) {
        int c = (64 + lane) * 4 + e;
        if (v1[e] > m) { m = v1[e]; mi = c; }
    }
    #pragma unroll
    for (int e = 0; e < 4; ++e) {
        int c = (128 + lane) * 4 + e;
        if (v2[e] > m) { m = v2[e]; mi = c; }
    }
    #pragma unroll
    for (int e = 0; e < 4; ++e) {
        int c = (192 + lane) * 4 + e;
        if (v3[e] > m) { m = v3[e]; mi = c; }
    }

    // ---- wave(64) butterfly argmax, tie -> lowest index (matches jnp.argmax) ----
    #pragma unroll
    for (int off = 32; off > 0; off >>= 1) {
        float om = __shfl_xor(m, off, 64);
        int   oi = __shfl_xor(mi, off, 64);
        if (om > m || (om == m && oi < mi)) { m = om; mi = oi; }
    }
    const int idx = mi;   // all lanes agree after butterfly

    if (lane == 0) out_idx[row] = (float)idx;

    // ---- gather basis[idx] (L2-resident) -> out_q[row], nontemporal stores ----
    const vfloat4* b4 = reinterpret_cast<const vfloat4*>(basis + (size_t)idx * D_DIM);
    vfloat4*       o4 = reinterpret_cast<vfloat4*>(out_q + (size_t)row * D_DIM);
    #pragma unroll
    for (int j = 0; j < 4; ++j) {
        int t = 64 * j + lane;
        if (t < 225) {
            vfloat4 bv = b4[t];                       // cached (keep in L2)
            __builtin_nontemporal_store(bv, &o4[t]); // stream out
        }
    }
}

extern "C" void kernel_launch(void* const* d_in, const int* in_sizes, int n_in,
                              void* d_out, int out_size, void* d_ws, size_t ws_size,
                              hipStream_t stream) {
    const float* latent = (const float*)d_in[0];   // 16*2048*1024
    const float* basis  = (const float*)d_in[1];   // 1024*900
    (void)n_in; (void)d_ws; (void)ws_size; (void)out_size;

    const int rows = in_sizes[0] / C_DIM;          // 32768
    float* out_q   = (float*)d_out;                // rows*900
    float* out_idx = (float*)d_out + (size_t)rows * D_DIM;

    const int blocks = (rows + 3) / 4;             // 4 rows (waves) per block
    basisvq_kernel<<<blocks, 256, 0, stream>>>(latent, basis, out_q, out_idx, rows);
}